// Round 9
// baseline (207.866 us; speedup 1.0000x reference)
//
#include <hip/hip_runtime.h>
#include <hip/hip_bf16.h>

#define D 128  // D_IN == D_OUT == 128

typedef __attribute__((ext_vector_type(8))) short bf16x8;  // 8 bf16 = 4 VGPRs
typedef __attribute__((ext_vector_type(4))) float f32x4;
typedef __attribute__((ext_vector_type(4))) uint  u32x4;   // native vec for nt stores

static __device__ __forceinline__ ushort f2bf(float f) {
    __hip_bfloat16 h = __float2bfloat16(f);  // RNE
    return *(ushort*)&h;
}
static __device__ __forceinline__ float bfl(uint u) { return __uint_as_float(u << 16); }
static __device__ __forceinline__ float bfh(uint u) { return __uint_as_float(u & 0xffff0000u); }

// ---------------- W swizzle: fp32 W[128][128] -> bf16 fragment-order Wz ----------------
// Wz[((ks*8+nb)*64 + lane)*8 + j] = bf16( W[ks*32 + (lane>>4)*8 + j][nb*16 + (lane&15)] )
__global__ __launch_bounds__(256) void swizzle_w(const float* __restrict__ W,
                                                 ushort* __restrict__ Wz)
{
    const int t = blockIdx.x * 256 + threadIdx.x;   // 0..2047 = (combo, lane)
    const int lane = t & 63;
    const int combo = t >> 6;                       // ks*8+nb, 0..31
    const int ks = combo >> 3, nb = combo & 7;
    const int krow = ks * 32 + ((lane >> 4) << 3);
    const int col  = nb * 16 + (lane & 15);
    ushort u[8];
    #pragma unroll
    for (int j = 0; j < 8; ++j) u[j] = f2bf(W[(krow + j) * D + col]);
    uint4 p;
    p.x = (uint)u[0] | ((uint)u[1] << 16);
    p.y = (uint)u[2] | ((uint)u[3] << 16);
    p.z = (uint)u[4] | ((uint)u[5] << 16);
    p.w = (uint)u[6] | ((uint)u[7] << 16);
    *(uint4*)(Wz + (size_t)t * 8) = p;
}

// ---------------- GEMM v5b: load-hoist + coalesced LDS-bounce epilogue ----------------
// R8 bug: drain loop ran 4 iters (64 B/thread) instead of 8 (128 B/thread),
// leaving half of every Xp row zero -> absmax 11.7. Fixed: i < 8.
// Issue order: (a) Wz stage loads -> regs, (b) X-frag loads+converts (their L3
// latency overlaps (a)), (c) LDS writes, (d) ONE barrier, (e) MFMA.
// Epilogue: results bounce through the dead W LDS buffer (row stride 136
// shorts; +8 pad -> ~2-way banks) and leave as fully-coalesced 16 B
// nontemporal stores (2 threads per 256 B row).
__global__ __launch_bounds__(256) void gemm_mfma(const float* __restrict__ X,
                                                 const ushort* __restrict__ Wz,
                                                 const float* __restrict__ deg,
                                                 ushort* __restrict__ Xp, int n)
{
    __shared__ ushort wsh[128 * 136];     // 34816 B; phase 1 uses first 32 KB
    const int tid  = threadIdx.x;
    const int lane = tid & 63;
    const int wave = tid >> 6;

    // (a) stage loads first: 8 coalesced uint4/thread from Wz (L2-resident)
    uint4 wreg[8];
    {
        const uint4* src = (const uint4*)Wz;
        #pragma unroll
        for (int i = 0; i < 8; ++i) wreg[i] = src[tid + i * 256];
    }

    // (b) X-frag build: these global loads issue behind (a); latency overlaps
    const int m = lane & 15, quad = lane >> 4;
    const int r0 = blockIdx.x * 128 + wave * 32;   // 2 tiles: rows r0..+15, +16..+31

    bf16x8 xfrag[2][4];
    #pragma unroll
    for (int t = 0; t < 2; ++t) {
        long long arow = r0 + t * 16 + m;
        if (arow >= n) arow = n - 1;               // clamp loads; stores guarded
        const float* xa = X + arow * D + quad * 8;
        #pragma unroll
        for (int ks = 0; ks < 4; ++ks) {
            float4 lo = *(const float4*)(xa + ks * 32);
            float4 hi = *(const float4*)(xa + ks * 32 + 4);
            bf16x8 a;
            a[0] = (short)f2bf(lo.x); a[1] = (short)f2bf(lo.y);
            a[2] = (short)f2bf(lo.z); a[3] = (short)f2bf(lo.w);
            a[4] = (short)f2bf(hi.x); a[5] = (short)f2bf(hi.y);
            a[6] = (short)f2bf(hi.z); a[7] = (short)f2bf(hi.w);
            xfrag[t][ks] = a;
        }
    }

    // (c) LDS writes of the staged W, (d) single barrier
    {
        uint4* dst = (uint4*)wsh;
        #pragma unroll
        for (int i = 0; i < 8; ++i) dst[tid + i * 256] = wreg[i];
    }
    __syncthreads();

    f32x4 acc[2][8];
    #pragma unroll
    for (int t = 0; t < 2; ++t)
        #pragma unroll
        for (int nb = 0; nb < 8; ++nb) acc[t][nb] = (f32x4){0.f, 0.f, 0.f, 0.f};

    #pragma unroll
    for (int nb = 0; nb < 8; ++nb) {
        #pragma unroll
        for (int ks = 0; ks < 4; ++ks) {
            bf16x8 w = *(const bf16x8*)(wsh + ((size_t)((ks * 8 + nb) * 64 + lane)) * 8);
            // swapped operands: D = (W^T tile)·(X^T tile) = (X·W)^T tile
            // -> lane holds row r0+t*16+m, cols nb*16+quad*4+{0..3}
            acc[0][nb] = __builtin_amdgcn_mfma_f32_16x16x32_bf16(w, xfrag[0][ks], acc[0][nb], 0, 0, 0);
            acc[1][nb] = __builtin_amdgcn_mfma_f32_16x16x32_bf16(w, xfrag[1][ks], acc[1][nb], 0, 0, 0);
        }
    }

    // epilogue: bounce through LDS (W copy is dead after the MFMA loop)
    __syncthreads();                       // all ds_reads of wsh retired
    #pragma unroll
    for (int t = 0; t < 2; ++t) {
        const int lr   = wave * 32 + t * 16 + m;        // local row 0..127
        const int grow = r0 + t * 16 + m;
        const float dr = (grow < n) ? deg[grow] : 0.f;
        #pragma unroll
        for (int nb = 0; nb < 8; ++nb) {
            uint2 p;
            p.x = (uint)f2bf(dr * acc[t][nb][0]) | ((uint)f2bf(dr * acc[t][nb][1]) << 16);
            p.y = (uint)f2bf(dr * acc[t][nb][2]) | ((uint)f2bf(dr * acc[t][nb][3]) << 16);
            *(uint2*)(wsh + lr * 136 + nb * 16 + quad * 4) = p;
        }
    }
    __syncthreads();
    {   // coalesced drain: 2 threads per 256 B row; 8 x 16 B nt stores each
        const int row  = tid >> 1, half = tid & 1;      // row 0..127
        const int grow = blockIdx.x * 128 + row;
        if (grow < n) {
            u32x4* dst = (u32x4*)(Xp + (size_t)grow * D + half * 64);
            const ushort* src = wsh + row * 136 + half * 64;
            #pragma unroll
            for (int i = 0; i < 8; ++i)    // 8 iters x 8 shorts = 64 shorts = 128 B
                __builtin_nontemporal_store(*(const u32x4*)(src + i * 8), dst + i);
        }
    }
}

// ---------------- SpMM v5 (exact, known 65.8 us): one wave per row ----------------
__global__ __launch_bounds__(256) void spmm_csr(const ushort* __restrict__ Xp,
                                                const float* __restrict__ deg,
                                                const int* __restrict__ rp,
                                                const int* __restrict__ ci,
                                                float* __restrict__ out, int n)
{
    int row = __builtin_amdgcn_readfirstlane(blockIdx.x * 4 + (threadIdx.x >> 6));
    if (row >= n) row = n - 1;            // uniform clamp (n%4==0: never taken)
    const int lane = threadIdx.x & 63;
    const int beg = rp[row];              // uniform -> s_load
    const int end = rp[row + 1];
    const uint* __restrict__ Xq = (const uint*)Xp;   // one bf16 row = 64 uints

    float a0 = 0.f, a1 = 0.f;             // parity-split accumulator pairs
    float b0 = 0.f, b1 = 0.f;

    int e = beg;
    for (; e + 8 <= end; e += 8) {
        const int c0 = ci[e + 0], c1 = ci[e + 1], c2 = ci[e + 2], c3 = ci[e + 3];
        const int c4 = ci[e + 4], c5 = ci[e + 5], c6 = ci[e + 6], c7 = ci[e + 7];
        const uint v0 = Xq[(size_t)c0 * 64 + lane];
        const uint v1 = Xq[(size_t)c1 * 64 + lane];
        const uint v2 = Xq[(size_t)c2 * 64 + lane];
        const uint v3 = Xq[(size_t)c3 * 64 + lane];
        const uint v4 = Xq[(size_t)c4 * 64 + lane];
        const uint v5 = Xq[(size_t)c5 * 64 + lane];
        const uint v6 = Xq[(size_t)c6 * 64 + lane];
        const uint v7 = Xq[(size_t)c7 * 64 + lane];
        a0 += bfl(v0); a1 += bfh(v0);
        b0 += bfl(v1); b1 += bfh(v1);
        a0 += bfl(v2); a1 += bfh(v2);
        b0 += bfl(v3); b1 += bfh(v3);
        a0 += bfl(v4); a1 += bfh(v4);
        b0 += bfl(v5); b1 += bfh(v5);
        a0 += bfl(v6); a1 += bfh(v6);
        b0 += bfl(v7); b1 += bfh(v7);
    }

    if (e < end) {                         // clamped tail batch, still 8-deep
        int cc[8];
        #pragma unroll
        for (int j = 0; j < 8; ++j) {
            const int ee = e + j;
            cc[j] = ci[ee < end ? ee : end - 1];
        }
        uint vv[8];
        #pragma unroll
        for (int j = 0; j < 8; ++j) vv[j] = Xq[(size_t)cc[j] * 64 + lane];
        #pragma unroll
        for (int j = 0; j < 8; ++j) {
            if (e + j < end) { a0 += bfl(vv[j]); a1 += bfh(vv[j]); }
        }
    }

    const float dr = deg[row];             // uniform -> s_load
    float2 o;
    o.x = dr * (a0 + b0);
    o.y = dr * (a1 + b1);
    *(float2*)(out + (size_t)row * D + lane * 2) = o;   // coalesced
}

extern "C" void kernel_launch(void* const* d_in, const int* in_sizes, int n_in,
                              void* d_out, int out_size, void* d_ws, size_t ws_size,
                              hipStream_t stream)
{
    const float* X   = (const float*)d_in[0];   // [N,128] fp32
    const float* W   = (const float*)d_in[1];   // [128,128] fp32
    const float* deg = (const float*)d_in[2];   // [N] fp32
    const int*   rp  = (const int*)d_in[3];     // [N+1] int32
    const int*   ci  = (const int*)d_in[4];     // [E] int32
    float* out = (float*)d_out;                 // [N,128] fp32
    const int n = in_sizes[2];                  // N = 100000

    ushort* Xp = (ushort*)d_ws;                 // X'' bf16: n*128*2 = 25.6 MB
    ushort* Wz = Xp + (size_t)n * D;            // swizzled bf16 W: 32 KB

    swizzle_w<<<8, 256, 0, stream>>>(W, Wz);
    gemm_mfma<<<(n + 127) / 128, 256, 0, stream>>>(X, Wz, deg, Xp, n);
    spmm_csr<<<(n + 3) / 4, 256, 0, stream>>>(Xp, deg, rp, ci, out, n);
}

// Round 10
// 174.347 us; speedup vs baseline: 1.1923x; 1.1923x over previous
//
#include <hip/hip_runtime.h>
#include <hip/hip_bf16.h>

#define D 128  // D_IN == D_OUT == 128

typedef __attribute__((ext_vector_type(8))) short bf16x8;  // 8 bf16 = 4 VGPRs
typedef __attribute__((ext_vector_type(4))) float f32x4;

static __device__ __forceinline__ ushort f2bf(float f) {
    __hip_bfloat16 h = __float2bfloat16(f);  // RNE
    return *(ushort*)&h;
}
static __device__ __forceinline__ float bfl(uint u) { return __uint_as_float(u << 16); }
static __device__ __forceinline__ float bfh(uint u) { return __uint_as_float(u & 0xffff0000u); }

// ---------------- W swizzle: fp32 W[128][128] -> bf16 fragment-order Wz ----------------
// Wz[((ks*8+nb)*64 + lane)*8 + j] = bf16( W[ks*32 + (lane>>4)*8 + j][nb*16 + (lane&15)] )
__global__ __launch_bounds__(256) void swizzle_w(const float* __restrict__ W,
                                                 ushort* __restrict__ Wz)
{
    const int t = blockIdx.x * 256 + threadIdx.x;   // 0..2047 = (combo, lane)
    const int lane = t & 63;
    const int combo = t >> 6;                       // ks*8+nb, 0..31
    const int ks = combo >> 3, nb = combo & 7;
    const int krow = ks * 32 + ((lane >> 4) << 3);
    const int col  = nb * 16 + (lane & 15);
    ushort u[8];
    #pragma unroll
    for (int j = 0; j < 8; ++j) u[j] = f2bf(W[(krow + j) * D + col]);
    uint4 p;
    p.x = (uint)u[0] | ((uint)u[1] << 16);
    p.y = (uint)u[2] | ((uint)u[3] << 16);
    p.z = (uint)u[4] | ((uint)u[5] << 16);
    p.w = (uint)u[6] | ((uint)u[7] << 16);
    *(uint4*)(Wz + (size_t)t * 8) = p;
}

// ---------------- GEMM v6: 64-row blocks (grid 1563) + direct uint2 epilogue ----------------
// R9 counters condemned the LDS-bounce/nt epilogue (WRITE 83.7 MB vs 25.6 ideal:
// stride-128 16 B nt chunks bypass L2 write-combining -> 3.3x HBM write
// amplification) and the 782-block grid (3.05 blocks/CU co-resident once ->
// occupancy avg 21% -> 1.64 TB/s latency wall). Fixes:
//  - epilogue reverted to R3's direct uint2 stores THROUGH L2 (lines become
//    fully dirty across the 8 nb stores; WRITE was exactly 25.6 MB in R0-R3)
//  - 64 rows/block, 1 M-tile/wave: 1563 blocks ~ 6.1/CU; 32 KB LDS caps 5
//    blocks/CU = 20 waves/CU resident -> ~2.5x the in-flight loads.
// Load-hoist kept: Wz stage loads issue first, X loads overlap their latency,
// one barrier total.
__global__ __launch_bounds__(256) void gemm_mfma(const float* __restrict__ X,
                                                 const ushort* __restrict__ Wz,
                                                 const float* __restrict__ deg,
                                                 ushort* __restrict__ Xp, int n)
{
    __shared__ ushort wsh[32 * 64 * 8];   // 32 KB fragment-order W copy
    const int tid  = threadIdx.x;
    const int lane = tid & 63;
    const int wave = tid >> 6;

    // (a) stage loads first: 8 coalesced uint4/thread from Wz (L2-resident)
    uint4 wreg[8];
    {
        const uint4* src = (const uint4*)Wz;
        #pragma unroll
        for (int i = 0; i < 8; ++i) wreg[i] = src[tid + i * 256];
    }

    // (b) X-frag build: one 16-row M-tile per wave; loads overlap (a)'s latency
    const int m = lane & 15, quad = lane >> 4;
    const int r0 = blockIdx.x * 64 + wave * 16;

    bf16x8 xfrag[4];
    {
        long long arow = r0 + m;
        if (arow >= n) arow = n - 1;               // clamp loads; stores guarded
        const float* xa = X + arow * D + quad * 8;
        #pragma unroll
        for (int ks = 0; ks < 4; ++ks) {
            float4 lo = *(const float4*)(xa + ks * 32);
            float4 hi = *(const float4*)(xa + ks * 32 + 4);
            bf16x8 a;
            a[0] = (short)f2bf(lo.x); a[1] = (short)f2bf(lo.y);
            a[2] = (short)f2bf(lo.z); a[3] = (short)f2bf(lo.w);
            a[4] = (short)f2bf(hi.x); a[5] = (short)f2bf(hi.y);
            a[6] = (short)f2bf(hi.z); a[7] = (short)f2bf(hi.w);
            xfrag[ks] = a;
        }
    }

    // (c) LDS writes of staged W, (d) single barrier
    {
        uint4* dst = (uint4*)wsh;
        #pragma unroll
        for (int i = 0; i < 8; ++i) dst[tid + i * 256] = wreg[i];
    }
    __syncthreads();

    f32x4 acc[8];
    #pragma unroll
    for (int nb = 0; nb < 8; ++nb) acc[nb] = (f32x4){0.f, 0.f, 0.f, 0.f};

    #pragma unroll
    for (int nb = 0; nb < 8; ++nb) {
        #pragma unroll
        for (int ks = 0; ks < 4; ++ks) {
            bf16x8 w = *(const bf16x8*)(wsh + ((size_t)((ks * 8 + nb) * 64 + lane)) * 8);
            // swapped operands: D = (W^T tile)·(X^T tile) = (X·W)^T tile
            // -> lane holds row r0+m, cols nb*16+quad*4+{0..3}
            acc[nb] = __builtin_amdgcn_mfma_f32_16x16x32_bf16(w, xfrag[ks], acc[nb], 0, 0, 0);
        }
    }

    // epilogue: direct uint2 stores through L2 (R3-verified; lines fully
    // dirtied across nb iterations -> exact 25.6 MB write-back, no nt)
    const int row = r0 + m;
    if (row < n) {
        const float dr = deg[row];
        ushort* dstrow = Xp + (size_t)row * D + quad * 4;
        #pragma unroll
        for (int nb = 0; nb < 8; ++nb) {
            uint2 p;
            p.x = (uint)f2bf(dr * acc[nb][0]) | ((uint)f2bf(dr * acc[nb][1]) << 16);
            p.y = (uint)f2bf(dr * acc[nb][2]) | ((uint)f2bf(dr * acc[nb][3]) << 16);
            *(uint2*)(dstrow + nb * 16) = p;   // 8 B store, 4 consecutive cols
        }
    }
}

// ---------------- SpMM v5 (exact, known 65.8 us): one wave per row ----------------
// At its wall: 235 MB of L2-miss traffic at ~3.5 TB/s (random 256 B lines via
// L3 fabric). v6 (flush machinery) and v7 (4 rows/wave) both regressed.
__global__ __launch_bounds__(256) void spmm_csr(const ushort* __restrict__ Xp,
                                                const float* __restrict__ deg,
                                                const int* __restrict__ rp,
                                                const int* __restrict__ ci,
                                                float* __restrict__ out, int n)
{
    int row = __builtin_amdgcn_readfirstlane(blockIdx.x * 4 + (threadIdx.x >> 6));
    if (row >= n) row = n - 1;            // uniform clamp (n%4==0: never taken)
    const int lane = threadIdx.x & 63;
    const int beg = rp[row];              // uniform -> s_load
    const int end = rp[row + 1];
    const uint* __restrict__ Xq = (const uint*)Xp;   // one bf16 row = 64 uints

    float a0 = 0.f, a1 = 0.f;             // parity-split accumulator pairs
    float b0 = 0.f, b1 = 0.f;

    int e = beg;
    for (; e + 8 <= end; e += 8) {
        const int c0 = ci[e + 0], c1 = ci[e + 1], c2 = ci[e + 2], c3 = ci[e + 3];
        const int c4 = ci[e + 4], c5 = ci[e + 5], c6 = ci[e + 6], c7 = ci[e + 7];
        const uint v0 = Xq[(size_t)c0 * 64 + lane];
        const uint v1 = Xq[(size_t)c1 * 64 + lane];
        const uint v2 = Xq[(size_t)c2 * 64 + lane];
        const uint v3 = Xq[(size_t)c3 * 64 + lane];
        const uint v4 = Xq[(size_t)c4 * 64 + lane];
        const uint v5 = Xq[(size_t)c5 * 64 + lane];
        const uint v6 = Xq[(size_t)c6 * 64 + lane];
        const uint v7 = Xq[(size_t)c7 * 64 + lane];
        a0 += bfl(v0); a1 += bfh(v0);
        b0 += bfl(v1); b1 += bfh(v1);
        a0 += bfl(v2); a1 += bfh(v2);
        b0 += bfl(v3); b1 += bfh(v3);
        a0 += bfl(v4); a1 += bfh(v4);
        b0 += bfl(v5); b1 += bfh(v5);
        a0 += bfl(v6); a1 += bfh(v6);
        b0 += bfl(v7); b1 += bfh(v7);
    }

    if (e < end) {                         // clamped tail batch, still 8-deep
        int cc[8];
        #pragma unroll
        for (int j = 0; j < 8; ++j) {
            const int ee = e + j;
            cc[j] = ci[ee < end ? ee : end - 1];
        }
        uint vv[8];
        #pragma unroll
        for (int j = 0; j < 8; ++j) vv[j] = Xq[(size_t)cc[j] * 64 + lane];
        #pragma unroll
        for (int j = 0; j < 8; ++j) {
            if (e + j < end) { a0 += bfl(vv[j]); a1 += bfh(vv[j]); }
        }
    }

    const float dr = deg[row];             // uniform -> s_load
    float2 o;
    o.x = dr * (a0 + b0);
    o.y = dr * (a1 + b1);
    *(float2*)(out + (size_t)row * D + lane * 2) = o;   // coalesced
}

extern "C" void kernel_launch(void* const* d_in, const int* in_sizes, int n_in,
                              void* d_out, int out_size, void* d_ws, size_t ws_size,
                              hipStream_t stream)
{
    const float* X   = (const float*)d_in[0];   // [N,128] fp32
    const float* W   = (const float*)d_in[1];   // [128,128] fp32
    const float* deg = (const float*)d_in[2];   // [N] fp32
    const int*   rp  = (const int*)d_in[3];     // [N+1] int32
    const int*   ci  = (const int*)d_in[4];     // [E] int32
    float* out = (float*)d_out;                 // [N,128] fp32
    const int n = in_sizes[2];                  // N = 100000

    ushort* Xp = (ushort*)d_ws;                 // X'' bf16: n*128*2 = 25.6 MB
    ushort* Wz = Xp + (size_t)n * D;            // swizzled bf16 W: 32 KB

    swizzle_w<<<8, 256, 0, stream>>>(W, Wz);
    gemm_mfma<<<(n + 63) / 64, 256, 0, stream>>>(X, Wz, deg, Xp, n);
    spmm_csr<<<(n + 3) / 4, 256, 0, stream>>>(Xp, deg, rp, ci, out, n);
}

// Round 11
// 173.222 us; speedup vs baseline: 1.2000x; 1.0065x over previous
//
#include <hip/hip_runtime.h>
#include <hip/hip_bf16.h>

#define D 128  // D_IN == D_OUT == 128

typedef __attribute__((ext_vector_type(8))) short bf16x8;  // 8 bf16 = 4 VGPRs
typedef __attribute__((ext_vector_type(4))) float f32x4;

static __device__ __forceinline__ ushort f2bf(float f) {
    __hip_bfloat16 h = __float2bfloat16(f);  // RNE
    return *(ushort*)&h;
}
static __device__ __forceinline__ float bfl(uint u) { return __uint_as_float(u << 16); }
static __device__ __forceinline__ float bfh(uint u) { return __uint_as_float(u & 0xffff0000u); }

// ---------------- W swizzle: fp32 W[128][128] -> bf16 fragment-order Wz ----------------
// Wz[((ks*8+nb)*64 + lane)*8 + j] = bf16( W[ks*32 + (lane>>4)*8 + j][nb*16 + (lane&15)] )
__global__ __launch_bounds__(256) void swizzle_w(const float* __restrict__ W,
                                                 ushort* __restrict__ Wz)
{
    const int t = blockIdx.x * 256 + threadIdx.x;   // 0..2047 = (combo, lane)
    const int lane = t & 63;
    const int combo = t >> 6;                       // ks*8+nb, 0..31
    const int ks = combo >> 3, nb = combo & 7;
    const int krow = ks * 32 + ((lane >> 4) << 3);
    const int col  = nb * 16 + (lane & 15);
    ushort u[8];
    #pragma unroll
    for (int j = 0; j < 8; ++j) u[j] = f2bf(W[(krow + j) * D + col]);
    uint4 p;
    p.x = (uint)u[0] | ((uint)u[1] << 16);
    p.y = (uint)u[2] | ((uint)u[3] << 16);
    p.z = (uint)u[4] | ((uint)u[5] << 16);
    p.w = (uint)u[6] | ((uint)u[7] << 16);
    *(uint4*)(Wz + (size_t)t * 8) = p;
}

// ---------------- GEMM v7: half-staged W (16 KB LDS) via global_load_lds ----------------
// R10 analysis: gemm ~24-25 us vs ~13 us floor, latency-bound, and LDS was the
// only occupancy cap (32 KB -> 5 blocks/CU = 20/32 wave slots; VGPR 56 < 64).
// Fix: stage W in two 16 KB halves (ks{0,1} then ks{2,3}) with
// global_load_lds width=16 (no VGPR round-trip -> stays under the 64-VGPR
// cliff). 16 KB -> 8 blocks/CU -> 32 waves/CU (100% of slots).
// Per-acc[nb] accumulation order stays ks=0,1,2,3 -> bitwise-identical output.
__global__ __launch_bounds__(256) void gemm_mfma(const float* __restrict__ X,
                                                 const ushort* __restrict__ Wz,
                                                 const float* __restrict__ deg,
                                                 ushort* __restrict__ Xp, int n)
{
    __shared__ ushort wsh[16 * 64 * 8];   // 16 KB: one half (16 combos) at a time
    const int tid  = threadIdx.x;
    const int lane = tid & 63;
    const int wave = tid >> 6;

    // X-frag build first: global loads issue immediately, latency overlaps
    // the first half's staging
    const int m = lane & 15, quad = lane >> 4;
    const int r0 = blockIdx.x * 64 + wave * 16;    // one 16-row M-tile per wave

    bf16x8 xfrag[4];
    {
        long long arow = r0 + m;
        if (arow >= n) arow = n - 1;               // clamp loads; stores guarded
        const float* xa = X + arow * D + quad * 8;
        #pragma unroll
        for (int ks = 0; ks < 4; ++ks) {
            float4 lo = *(const float4*)(xa + ks * 32);
            float4 hi = *(const float4*)(xa + ks * 32 + 4);
            bf16x8 a;
            a[0] = (short)f2bf(lo.x); a[1] = (short)f2bf(lo.y);
            a[2] = (short)f2bf(lo.z); a[3] = (short)f2bf(lo.w);
            a[4] = (short)f2bf(hi.x); a[5] = (short)f2bf(hi.y);
            a[6] = (short)f2bf(hi.z); a[7] = (short)f2bf(hi.w);
            xfrag[ks] = a;
        }
    }

    f32x4 acc[8];
    #pragma unroll
    for (int nb = 0; nb < 8; ++nb) acc[nb] = (f32x4){0.f, 0.f, 0.f, 0.f};

    #pragma unroll
    for (int h = 0; h < 2; ++h) {
        if (h) __syncthreads();            // half-0 compute done before overwrite
        // stage this half: 4 x global_load_lds width=16; linear lane-order
        // dest (slot = tid + i*256) == wave-uniform base + lane*16  ✓
        #pragma unroll
        for (int i = 0; i < 4; ++i) {
            const int slot = tid + i * 256;                 // 0..1023 (local)
            __builtin_amdgcn_global_load_lds(
                (const uint*)(Wz + ((size_t)(h * 1024 + slot)) * 8),
                (uint*)(wsh + (size_t)slot * 8), 16, 0, 0);
        }
        __syncthreads();                   // staged half visible

        #pragma unroll
        for (int nb = 0; nb < 8; ++nb) {
            #pragma unroll
            for (int k2 = 0; k2 < 2; ++k2) {   // global ks = h*2 + k2
                bf16x8 w = *(const bf16x8*)(wsh + ((size_t)((k2 * 8 + nb) * 64 + lane)) * 8);
                // swapped operands: D = (W^T tile)·(X^T tile) = (X·W)^T tile
                // -> lane holds row r0+m, cols nb*16+quad*4+{0..3}
                acc[nb] = __builtin_amdgcn_mfma_f32_16x16x32_bf16(w, xfrag[h * 2 + k2], acc[nb], 0, 0, 0);
            }
        }
    }

    // epilogue: direct uint2 stores through L2 (R10-verified: WRITE = 25.6 MB)
    const int row = r0 + m;
    if (row < n) {
        const float dr = deg[row];
        ushort* dstrow = Xp + (size_t)row * D + quad * 4;
        #pragma unroll
        for (int nb = 0; nb < 8; ++nb) {
            uint2 p;
            p.x = (uint)f2bf(dr * acc[nb][0]) | ((uint)f2bf(dr * acc[nb][1]) << 16);
            p.y = (uint)f2bf(dr * acc[nb][2]) | ((uint)f2bf(dr * acc[nb][3]) << 16);
            *(uint2*)(dstrow + nb * 16) = p;   // 8 B store, 4 consecutive cols
        }
    }
}

// ---------------- SpMM v5 (exact, known 65.8-66.0 us): one wave per row ----------------
// At its wall: 235 MB of beyond-L2 traffic at ~3.6 TB/s (random 256 B lines);
// v6 (flush machinery), v7 (4 rows/wave), and persistent-fused all regressed.
__global__ __launch_bounds__(256) void spmm_csr(const ushort* __restrict__ Xp,
                                                const float* __restrict__ deg,
                                                const int* __restrict__ rp,
                                                const int* __restrict__ ci,
                                                float* __restrict__ out, int n)
{
    int row = __builtin_amdgcn_readfirstlane(blockIdx.x * 4 + (threadIdx.x >> 6));
    if (row >= n) row = n - 1;            // uniform clamp (n%4==0: never taken)
    const int lane = threadIdx.x & 63;
    const int beg = rp[row];              // uniform -> s_load
    const int end = rp[row + 1];
    const uint* __restrict__ Xq = (const uint*)Xp;   // one bf16 row = 64 uints

    float a0 = 0.f, a1 = 0.f;             // parity-split accumulator pairs
    float b0 = 0.f, b1 = 0.f;

    int e = beg;
    for (; e + 8 <= end; e += 8) {
        const int c0 = ci[e + 0], c1 = ci[e + 1], c2 = ci[e + 2], c3 = ci[e + 3];
        const int c4 = ci[e + 4], c5 = ci[e + 5], c6 = ci[e + 6], c7 = ci[e + 7];
        const uint v0 = Xq[(size_t)c0 * 64 + lane];
        const uint v1 = Xq[(size_t)c1 * 64 + lane];
        const uint v2 = Xq[(size_t)c2 * 64 + lane];
        const uint v3 = Xq[(size_t)c3 * 64 + lane];
        const uint v4 = Xq[(size_t)c4 * 64 + lane];
        const uint v5 = Xq[(size_t)c5 * 64 + lane];
        const uint v6 = Xq[(size_t)c6 * 64 + lane];
        const uint v7 = Xq[(size_t)c7 * 64 + lane];
        a0 += bfl(v0); a1 += bfh(v0);
        b0 += bfl(v1); b1 += bfh(v1);
        a0 += bfl(v2); a1 += bfh(v2);
        b0 += bfl(v3); b1 += bfh(v3);
        a0 += bfl(v4); a1 += bfh(v4);
        b0 += bfl(v5); b1 += bfh(v5);
        a0 += bfl(v6); a1 += bfh(v6);
        b0 += bfl(v7); b1 += bfh(v7);
    }

    if (e < end) {                         // clamped tail batch, still 8-deep
        int cc[8];
        #pragma unroll
        for (int j = 0; j < 8; ++j) {
            const int ee = e + j;
            cc[j] = ci[ee < end ? ee : end - 1];
        }
        uint vv[8];
        #pragma unroll
        for (int j = 0; j < 8; ++j) vv[j] = Xq[(size_t)cc[j] * 64 + lane];
        #pragma unroll
        for (int j = 0; j < 8; ++j) {
            if (e + j < end) { a0 += bfl(vv[j]); a1 += bfh(vv[j]); }
        }
    }

    const float dr = deg[row];             // uniform -> s_load
    float2 o;
    o.x = dr * (a0 + b0);
    o.y = dr * (a1 + b1);
    *(float2*)(out + (size_t)row * D + lane * 2) = o;   // coalesced
}

extern "C" void kernel_launch(void* const* d_in, const int* in_sizes, int n_in,
                              void* d_out, int out_size, void* d_ws, size_t ws_size,
                              hipStream_t stream)
{
    const float* X   = (const float*)d_in[0];   // [N,128] fp32
    const float* W   = (const float*)d_in[1];   // [128,128] fp32
    const float* deg = (const float*)d_in[2];   // [N] fp32
    const int*   rp  = (const int*)d_in[3];     // [N+1] int32
    const int*   ci  = (const int*)d_in[4];     // [E] int32
    float* out = (float*)d_out;                 // [N,128] fp32
    const int n = in_sizes[2];                  // N = 100000

    ushort* Xp = (ushort*)d_ws;                 // X'' bf16: n*128*2 = 25.6 MB
    ushort* Wz = Xp + (size_t)n * D;            // swizzled bf16 W: 32 KB

    swizzle_w<<<8, 256, 0, stream>>>(W, Wz);
    gemm_mfma<<<(n + 63) / 64, 256, 0, stream>>>(X, Wz, deg, Xp, n);
    spmm_csr<<<(n + 3) / 4, 256, 0, stream>>>(Xp, deg, rp, ci, out, n);
}